// Round 1
// 1661.652 us; speedup vs baseline: 1.0297x; 1.0297x over previous
//
#include <hip/hip_runtime.h>
#include <hip/hip_bf16.h>

typedef __bf16 bf16;
typedef __bf16 bf16x8 __attribute__((ext_vector_type(8)));
typedef float  f32x4  __attribute__((ext_vector_type(4)));
typedef float  f32x16 __attribute__((ext_vector_type(16)));

#define BATCH   16384
#define VOCAB   100000
#define NSPARSE 26

#define GLOBAL_AS __attribute__((address_space(1)))
#define LDS_AS    __attribute__((address_space(3)))

__device__ __forceinline__ void async_copy16(const bf16* g, bf16* l) {
    __builtin_amdgcn_global_load_lds((const GLOBAL_AS void*)g, (LDS_AS void*)l, 16, 0, 0);
}

// ---------------------------------------------------------------------------
// Merged weight transpose+convert, all 6 weights in one launch.
// LDS-tiled 32x32: coalesced reads along n, coalesced writes along k.
// wt[n][k] = (bf16) w[k][n], zero-pad k >= K up to Kpad.
// ---------------------------------------------------------------------------
__global__ __launch_bounds__(256) void transpose_all_kernel(
        const float* __restrict__ bw1, const float* __restrict__ bw2,
        const float* __restrict__ tw0, const float* __restrict__ tw1,
        const float* __restrict__ tw2, const float* __restrict__ tw3,
        bf16* __restrict__ wtb1, bf16* __restrict__ wtb2,
        bf16* __restrict__ wtt0, bf16* __restrict__ wtt1,
        bf16* __restrict__ wtt2, bf16* __restrict__ wtt3) {
    __shared__ float ld[32][33];
    int bid = blockIdx.x;
    const float* src; bf16* dst; int K, N, Kpad, tid;
    if (bid < 128)       { src = bw1; dst = wtb1; K = 512;  N = 256;  Kpad = 512;  tid = bid; }
    else if (bid < 160)  { src = bw2; dst = wtb2; K = 256;  N = 128;  Kpad = 256;  tid = bid - 128; }
    else if (bid < 672)  { src = tw0; dst = wtt0; K = 506;  N = 1024; Kpad = 512;  tid = bid - 160; }
    else if (bid < 1696) { src = tw1; dst = wtt1; K = 1024; N = 1024; Kpad = 1024; tid = bid - 672; }
    else if (bid < 2208) { src = tw2; dst = wtt2; K = 1024; N = 512;  Kpad = 1024; tid = bid - 1696; }
    else                 { src = tw3; dst = wtt3; K = 512;  N = 256;  Kpad = 512;  tid = bid - 2208; }
    int tilesK = Kpad >> 5;
    int tk = tid % tilesK, tn = tid / tilesK;
    int k0 = tk * 32, n0 = tn * 32;
    int tx = threadIdx.x & 31, ty = threadIdx.x >> 5;
    #pragma unroll
    for (int p = 0; p < 4; ++p) {
        int kr = p * 8 + ty;
        int gk = k0 + kr;
        ld[kr][tx] = (gk < K) ? src[(size_t)gk * N + n0 + tx] : 0.f;
    }
    __syncthreads();
    #pragma unroll
    for (int p = 0; p < 4; ++p) {
        int nr = p * 8 + ty;
        dst[(size_t)(n0 + nr) * Kpad + k0 + tx] = (bf16)ld[tx][nr];
    }
}

// ---------------------------------------------------------------------------
// Bottom layer 0: h0 = relu(dense @ bw0 + bb0), dense 16384x13 fp32, bw0 13x512
// ---------------------------------------------------------------------------
__global__ __launch_bounds__(256) void bot0_kernel(const float* __restrict__ dense,
                                                   const float* __restrict__ w,
                                                   const float* __restrict__ b,
                                                   bf16* __restrict__ h0) {
    __shared__ float ws_[13 * 512];
    __shared__ float ds_[8 * 13];
    int t  = threadIdx.x;
    int r0 = blockIdx.x * 8;
    for (int i = t; i < 13 * 512; i += 256) ws_[i] = w[i];
    for (int i = t; i < 8 * 13;   i += 256) ds_[i] = dense[(size_t)r0 * 13 + i];
    __syncthreads();
    float acc[8][2];
    for (int r = 0; r < 8; r++) { acc[r][0] = 0.f; acc[r][1] = 0.f; }
    for (int k = 0; k < 13; k++) {
        float w0 = ws_[k * 512 + t];
        float w1 = ws_[k * 512 + t + 256];
        for (int r = 0; r < 8; r++) {
            float d = ds_[r * 13 + k];
            acc[r][0] += d * w0;
            acc[r][1] += d * w1;
        }
    }
    float b0 = b[t], b1 = b[t + 256];
    for (int r = 0; r < 8; r++) {
        h0[(size_t)(r0 + r) * 512 + t]       = (bf16)fmaxf(acc[r][0] + b0, 0.f);
        h0[(size_t)(r0 + r) * 512 + t + 256] = (bf16)fmaxf(acc[r][1] + b1, 0.f);
    }
}

// ---------------------------------------------------------------------------
// Generic MFMA GEMM (m97-style 128x128, BK=32): used for the small layers.
// ---------------------------------------------------------------------------
__global__ __launch_bounds__(256) void gemm_kernel(const bf16* __restrict__ A,
                                                   const bf16* __restrict__ Wt,
                                                   const float* __restrict__ bias,
                                                   bf16* __restrict__ C,
                                                   int M, int N, int K, int do_relu) {
    __shared__ bf16 As[128 * 32];
    __shared__ bf16 Ws[128 * 32];
    const int t    = threadIdx.x;
    const int wave = t >> 6;
    const int lane = t & 63;
    const int m0   = blockIdx.x * 128;
    const int n0   = blockIdx.y * 128;
    const int wm   = (wave & 1) * 64;
    const int wn   = (wave >> 1) * 64;
    const int q    = lane >> 4;
    const int l16  = lane & 15;

    const int srow = t >> 2;
    const int scol = (t & 3) * 8;
    const bf16* ag = A  + (size_t)(m0 + srow) * K + scol;
    const bf16* wg = Wt + (size_t)(n0 + srow) * K + scol;
    const size_t rowK64 = (size_t)64 * K;
    bf16* lA0 = &As[srow * 32 + scol];
    bf16* lA1 = &As[(64 + srow) * 32 + scol];
    bf16* lW0 = &Ws[srow * 32 + scol];
    bf16* lW1 = &Ws[(64 + srow) * 32 + scol];

    f32x4 acc[4][4];
    for (int mi = 0; mi < 4; mi++)
        for (int ni = 0; ni < 4; ni++)
            for (int r = 0; r < 4; r++) acc[mi][ni][r] = 0.f;

    for (int bk = 0; bk < K; bk += 32) {
        async_copy16(ag + bk,          lA0);
        async_copy16(ag + bk + rowK64, lA1);
        async_copy16(wg + bk,          lW0);
        async_copy16(wg + bk + rowK64, lW1);
        __syncthreads();
        bf16x8 af[4], bfr[4];
        for (int i = 0; i < 4; i++)
            af[i]  = *(const bf16x8*)&As[(wm + i * 16 + l16) * 32 + q * 8];
        for (int i = 0; i < 4; i++)
            bfr[i] = *(const bf16x8*)&Ws[(wn + i * 16 + l16) * 32 + q * 8];
        for (int mi = 0; mi < 4; mi++)
            for (int ni = 0; ni < 4; ni++)
                acc[mi][ni] = __builtin_amdgcn_mfma_f32_16x16x32_bf16(
                    af[mi], bfr[ni], acc[mi][ni], 0, 0, 0);
        __syncthreads();
    }

    for (int ni = 0; ni < 4; ni++) {
        int gn = n0 + wn + ni * 16 + l16;
        float bv = bias[gn];
        for (int mi = 0; mi < 4; mi++) {
            int gm = m0 + wm + mi * 16 + q * 4;
            for (int r = 0; r < 4; r++) {
                float v = acc[mi][ni][r] + bv;
                if (do_relu) v = fmaxf(v, 0.f);
                C[(size_t)(gm + r) * N + gn] = (bf16)v;
            }
        }
    }
}

// ---------------------------------------------------------------------------
// 256x256 / BK=64 / 8-wave / 8-phase GEMM (T1+T2+T3+T4+T5 stack).
//  - LDS layout: row-major [256][64] bf16 per tensor per dbuf, with 16B-block
//    XOR swizzle blkS = blk ^ (row&7). global_load_lds writes linearly; the
//    swizzle is applied by permuting the per-lane GLOBAL source address
//    (rule 21: linear dest + inverse-swz source + swz on read). ds_read_b128
//    fragment reads then hit 8 distinct bank-quads per 8 lanes => 2-way
//    aliasing only (free, m136).
//  - Stage schedule (quadrant-matched, race-free by construction):
//      window w consumes tile T_w from buf[w&1] in 4 phases:
//        p0: (mi0-3 x ni0-1)  reads A-Q0(rows 0-63,128-191) + B-Q0
//        p1: (mi0-3 x ni2-3)  reads B-Q1
//        p2: (mi4-7 x ni0-1)  reads A-Q1(rows 64-127,192-255)
//        p3: (mi4-7 x ni2-3)  registers only
//      issues: p0 -> A-Q1 of T_{w+1} (other buf, region dead since w-1.p2)
//              p1 -> A-Q0 of T_{w+2} (this buf, dead after p0 end-barrier)
//              p2 -> B-Q0 of T_{w+2} (dead after p0)
//              p3 -> B-Q1 of T_{w+2} (dead after p1)
//      single s_waitcnt vmcnt(6) per window at p3 (3 half-tiles = 6 loads
//      in flight) provably completes all of T_{w+1} before its window.
// ---------------------------------------------------------------------------
__device__ __forceinline__ void stage_q(bf16* Ls, const bf16* G, int K, int qd,
                                        int kt, int t) {
    int r0   = qd * 64 + (t >> 3);
    int blkS = t & 7;
    int blk  = blkS ^ (r0 & 7);      // (r0+128)&7 == r0&7
    async_copy16(G + (size_t)r0 * K + kt * 64 + blk * 8,
                 Ls + r0 * 64 + blkS * 8);
    int r1 = r0 + 128;
    async_copy16(G + (size_t)r1 * K + kt * 64 + blk * 8,
                 Ls + r1 * 64 + blkS * 8);
}

__global__ __launch_bounds__(512, 2) void gemm256_kernel(const bf16* __restrict__ A,
                                                         const bf16* __restrict__ Wt,
                                                         const float* __restrict__ bias,
                                                         bf16* __restrict__ C,
                                                         int M, int N, int K, int do_relu) {
    __shared__ __align__(16) bf16 As[2][256 * 64];
    __shared__ __align__(16) bf16 Bs[2][256 * 64];
    const int t    = threadIdx.x;
    const int lane = t & 63;
    const int wv   = t >> 6;
    const int wr   = wv >> 2;        // 0..1 : 128 output rows
    const int wc   = wv & 3;         // 0..3 : 64 output cols
    const int l16  = lane & 15;
    const int qd4  = lane >> 4;

    // XCD-bijective block swizzle: contiguous chunks of (same-nt) tiles per XCD
    const int nmt = gridDim.x;
    const int nwg = gridDim.x * gridDim.y;
    int lin = blockIdx.x + nmt * blockIdx.y;
    int swz = ((nwg & 7) == 0) ? ((lin & 7) * (nwg >> 3) + (lin >> 3)) : lin;
    const int m0 = (swz % nmt) * 256;
    const int n0 = (swz / nmt) * 256;

    const bf16* Ag = A  + (size_t)m0 * K;
    const bf16* Bg = Wt + (size_t)n0 * K;
    const int NW = K >> 6;

    f32x4 acc[8][4];
    #pragma unroll
    for (int mi = 0; mi < 8; mi++)
        #pragma unroll
        for (int ni = 0; ni < 4; ni++)
            #pragma unroll
            for (int r = 0; r < 4; r++) acc[mi][ni][r] = 0.f;

    // prologue: T0 fully, T1 all but A-Q1; leave T1's 3 half-tiles in flight
    stage_q(&As[0][0], Ag, K, 0, 0, t);
    stage_q(&As[0][0], Ag, K, 1, 0, t);
    stage_q(&Bs[0][0], Bg, K, 0, 0, t);
    stage_q(&Bs[0][0], Bg, K, 1, 0, t);
    if (NW > 1) {
        stage_q(&As[1][0], Ag, K, 0, 1, t);
        stage_q(&Bs[1][0], Bg, K, 0, 1, t);
        stage_q(&Bs[1][0], Bg, K, 1, 1, t);
        asm volatile("s_waitcnt vmcnt(6)" ::: "memory");
    } else {
        asm volatile("s_waitcnt vmcnt(0)" ::: "memory");
    }
    __builtin_amdgcn_s_barrier();
    __builtin_amdgcn_sched_barrier(0);

    bf16x8 af[4][2], bq0[2][2], bq1[2][2];

    for (int w = 0; w < NW; ++w) {
        const int db = w & 1;
        bf16* Ab = &As[db][0];
        bf16* Bb = &Bs[db][0];
        bf16* Ao = &As[db ^ 1][0];

        // ---- phase 0: (mi0-3 x ni0-1), 12 ds_read_b128
        #pragma unroll
        for (int mi = 0; mi < 4; ++mi) {
            int row = wr * 128 + mi * 16 + l16;
            #pragma unroll
            for (int kk = 0; kk < 2; ++kk)
                af[mi][kk] = *(const bf16x8*)(Ab + row * 64 + (((kk * 4 + qd4) ^ (row & 7)) * 8));
        }
        #pragma unroll
        for (int ni = 0; ni < 2; ++ni) {
            int row = wc * 64 + ni * 16 + l16;
            #pragma unroll
            for (int kk = 0; kk < 2; ++kk)
                bq0[ni][kk] = *(const bf16x8*)(Bb + row * 64 + (((kk * 4 + qd4) ^ (row & 7)) * 8));
        }
        if (w + 1 < NW) stage_q(Ao, Ag, K, 1, w + 1, t);
        __builtin_amdgcn_s_barrier();
        __builtin_amdgcn_sched_barrier(0);
        __builtin_amdgcn_s_setprio(1);
        #pragma unroll
        for (int kk = 0; kk < 2; ++kk)
            #pragma unroll
            for (int mi = 0; mi < 4; ++mi)
                #pragma unroll
                for (int ni = 0; ni < 2; ++ni)
                    acc[mi][ni] = __builtin_amdgcn_mfma_f32_16x16x32_bf16(
                        af[mi][kk], bq0[ni][kk], acc[mi][ni], 0, 0, 0);
        __builtin_amdgcn_s_setprio(0);
        __builtin_amdgcn_sched_barrier(0);
        __builtin_amdgcn_s_barrier();
        __builtin_amdgcn_sched_barrier(0);

        // ---- phase 1: (mi0-3 x ni2-3), 4 ds_read_b128
        #pragma unroll
        for (int ni = 0; ni < 2; ++ni) {
            int row = wc * 64 + (ni + 2) * 16 + l16;
            #pragma unroll
            for (int kk = 0; kk < 2; ++kk)
                bq1[ni][kk] = *(const bf16x8*)(Bb + row * 64 + (((kk * 4 + qd4) ^ (row & 7)) * 8));
        }
        if (w + 2 < NW) stage_q(Ab, Ag, K, 0, w + 2, t);
        __builtin_amdgcn_s_barrier();
        __builtin_amdgcn_sched_barrier(0);
        __builtin_amdgcn_s_setprio(1);
        #pragma unroll
        for (int kk = 0; kk < 2; ++kk)
            #pragma unroll
            for (int mi = 0; mi < 4; ++mi)
                #pragma unroll
                for (int ni = 0; ni < 2; ++ni)
                    acc[mi][ni + 2] = __builtin_amdgcn_mfma_f32_16x16x32_bf16(
                        af[mi][kk], bq1[ni][kk], acc[mi][ni + 2], 0, 0, 0);
        __builtin_amdgcn_s_setprio(0);
        __builtin_amdgcn_sched_barrier(0);
        __builtin_amdgcn_s_barrier();
        __builtin_amdgcn_sched_barrier(0);

        // ---- phase 2: (mi4-7 x ni0-1), 8 ds_read_b128
        #pragma unroll
        for (int mi = 0; mi < 4; ++mi) {
            int row = wr * 128 + (mi + 4) * 16 + l16;
            #pragma unroll
            for (int kk = 0; kk < 2; ++kk)
                af[mi][kk] = *(const bf16x8*)(Ab + row * 64 + (((kk * 4 + qd4) ^ (row & 7)) * 8));
        }
        if (w + 2 < NW) stage_q(Bb, Bg, K, 0, w + 2, t);
        __builtin_amdgcn_s_barrier();
        __builtin_amdgcn_sched_barrier(0);
        __builtin_amdgcn_s_setprio(1);
        #pragma unroll
        for (int kk = 0; kk < 2; ++kk)
            #pragma unroll
            for (int mi = 0; mi < 4; ++mi)
                #pragma unroll
                for (int ni = 0; ni < 2; ++ni)
                    acc[mi + 4][ni] = __builtin_amdgcn_mfma_f32_16x16x32_bf16(
                        af[mi][kk], bq0[ni][kk], acc[mi + 4][ni], 0, 0, 0);
        __builtin_amdgcn_s_setprio(0);
        __builtin_amdgcn_sched_barrier(0);
        __builtin_amdgcn_s_barrier();
        __builtin_amdgcn_sched_barrier(0);

        // ---- phase 3: (mi4-7 x ni2-3), registers only; counted vmcnt
        if (w + 2 < NW) stage_q(Bb, Bg, K, 1, w + 2, t);
        __builtin_amdgcn_s_barrier();
        __builtin_amdgcn_sched_barrier(0);
        __builtin_amdgcn_s_setprio(1);
        #pragma unroll
        for (int kk = 0; kk < 2; ++kk)
            #pragma unroll
            for (int mi = 0; mi < 4; ++mi)
                #pragma unroll
                for (int ni = 0; ni < 2; ++ni)
                    acc[mi + 4][ni + 2] = __builtin_amdgcn_mfma_f32_16x16x32_bf16(
                        af[mi][kk], bq1[ni][kk], acc[mi + 4][ni + 2], 0, 0, 0);
        __builtin_amdgcn_s_setprio(0);
        __builtin_amdgcn_sched_barrier(0);
        if (w + 2 < NW) asm volatile("s_waitcnt vmcnt(6)" ::: "memory");
        else            asm volatile("s_waitcnt vmcnt(0)" ::: "memory");
        __builtin_amdgcn_s_barrier();
        __builtin_amdgcn_sched_barrier(0);
    }

    // epilogue: C/D map 16x16: col = lane&15, row = (lane>>4)*4 + reg
    #pragma unroll
    for (int ni = 0; ni < 4; ++ni) {
        int gn = n0 + wc * 64 + ni * 16 + l16;
        float bv = bias[gn];
        #pragma unroll
        for (int mi = 0; mi < 8; ++mi) {
            int gm = m0 + wr * 128 + mi * 16 + qd4 * 4;
            #pragma unroll
            for (int r = 0; r < 4; ++r) {
                float v = acc[mi][ni][r] + bv;
                if (do_relu) v = fmaxf(v, 0.f);
                C[(size_t)(gm + r) * N + gn] = (bf16)v;
            }
        }
    }
}

// ---------------------------------------------------------------------------
// Interaction: one wave per sample. F = [bot_out; emb rows] (27x128, pad 32).
// ---------------------------------------------------------------------------
__global__ __launch_bounds__(256) void interact_kernel(const int* __restrict__ cat,
                                                       const float* __restrict__ emb,
                                                       const bf16* __restrict__ bot,
                                                       bf16* __restrict__ top_in) {
    int wave = threadIdx.x >> 6;
    int lane = threadIdx.x & 63;
    int s = blockIdx.x * 4 + wave;
    int m = lane & 31;
    int h = lane >> 5;

    const float* erow = nullptr;
    if (m >= 1 && m <= NSPARSE) {
        int idx = cat[(size_t)s * NSPARSE + (m - 1)] + (m - 1) * VOCAB;
        erow = emb + (size_t)idx * 128;
    }
    const bf16* botp = bot + (size_t)s * 128;

    f32x16 acc;
    for (int r = 0; r < 16; r++) acc[r] = 0.f;

    for (int ck = 0; ck < 8; ck++) {
        bf16x8 frag;
        if (m == 0) {
            frag = *(const bf16x8*)(botp + ck * 16 + h * 8);
        } else if (erow) {
            const float4* rp = (const float4*)(erow + ck * 16 + h * 8);
            float4 u = rp[0], v = rp[1];
            frag[0] = (bf16)u.x; frag[1] = (bf16)u.y; frag[2] = (bf16)u.z; frag[3] = (bf16)u.w;
            frag[4] = (bf16)v.x; frag[5] = (bf16)v.y; frag[6] = (bf16)v.z; frag[7] = (bf16)v.w;
        } else {
            for (int j = 0; j < 8; j++) frag[j] = (bf16)0.f;
        }
        acc = __builtin_amdgcn_mfma_f32_32x32x16_bf16(frag, frag, acc, 0, 0, 0);
    }

    bf16* tp = top_in + (size_t)s * 512;
    ((unsigned int*)tp)[lane] = ((const unsigned int*)botp)[lane];
    if (lane < 3) ((unsigned int*)tp)[253 + lane] = 0u;
    for (int r = 0; r < 16; r++) {
        int row = (r & 3) + 8 * (r >> 2) + 4 * h;
        int col = m;
        if (row <= col && col <= NSPARSE) {
            int tpos = row * 27 - (row * (row - 1)) / 2 + (col - row);
            tp[128 + tpos] = (bf16)acc[r];
        }
    }
}

// ---------------------------------------------------------------------------
// Final layer: out[s] = h[s][0:256] . w + b
// ---------------------------------------------------------------------------
__global__ __launch_bounds__(256) void out_kernel(const bf16* __restrict__ h,
                                                  const float* __restrict__ w,
                                                  const float* __restrict__ b,
                                                  float* __restrict__ out) {
    int wave = threadIdx.x >> 6;
    int lane = threadIdx.x & 63;
    int s = blockIdx.x * 4 + wave;
    const bf16* hp = h + (size_t)s * 256;
    float sum = 0.f;
    for (int j = 0; j < 4; j++)
        sum += (float)hp[lane * 4 + j] * w[lane * 4 + j];
    for (int off = 32; off > 0; off >>= 1)
        sum += __shfl_down(sum, off, 64);
    if (lane == 0) out[s] = sum + b[0];
}

// ---------------------------------------------------------------------------
extern "C" void kernel_launch(void* const* d_in, const int* in_sizes, int n_in,
                              void* d_out, int out_size, void* d_ws, size_t ws_size,
                              hipStream_t stream) {
    const float* dense = (const float*)d_in[0];
    const int*   cat   = (const int*)d_in[1];
    const float* emb   = (const float*)d_in[2];
    const float* bw0   = (const float*)d_in[3];
    const float* bb0   = (const float*)d_in[4];
    const float* bw1   = (const float*)d_in[5];
    const float* bb1   = (const float*)d_in[6];
    const float* bw2   = (const float*)d_in[7];
    const float* bb2   = (const float*)d_in[8];
    const float* tw0   = (const float*)d_in[9];
    const float* tb0   = (const float*)d_in[10];
    const float* tw1   = (const float*)d_in[11];
    const float* tb1   = (const float*)d_in[12];
    const float* tw2   = (const float*)d_in[13];
    const float* tb2   = (const float*)d_in[14];
    const float* tw3   = (const float*)d_in[15];
    const float* tb3   = (const float*)d_in[16];
    const float* tw4   = (const float*)d_in[17];
    const float* tb4   = (const float*)d_in[18];
    float* out = (float*)d_out;

    char* ws = (char*)d_ws;
    bf16* bufA = (bf16*)ws;  ws += (size_t)BATCH * 1024 * sizeof(bf16);
    bf16* bufB = (bf16*)ws;  ws += (size_t)BATCH * 1024 * sizeof(bf16);
    bf16* wtb1 = (bf16*)ws;  ws += (size_t)256  * 512  * sizeof(bf16);
    bf16* wtb2 = (bf16*)ws;  ws += (size_t)128  * 256  * sizeof(bf16);
    bf16* wtt0 = (bf16*)ws;  ws += (size_t)1024 * 512  * sizeof(bf16);
    bf16* wtt1 = (bf16*)ws;  ws += (size_t)1024 * 1024 * sizeof(bf16);
    bf16* wtt2 = (bf16*)ws;  ws += (size_t)512  * 1024 * sizeof(bf16);
    bf16* wtt3 = (bf16*)ws;  ws += (size_t)256  * 512  * sizeof(bf16);

    // all weight transposes in one launch (2336 tiles total)
    transpose_all_kernel<<<2336, 256, 0, stream>>>(bw1, bw2, tw0, tw1, tw2, tw3,
                                                   wtb1, wtb2, wtt0, wtt1, wtt2, wtt3);

    // bottom MLP
    bot0_kernel<<<BATCH / 8, 256, 0, stream>>>(dense, bw0, bb0, bufA);               // h0 -> A (512)
    gemm_kernel<<<dim3(BATCH / 128, 2), 256, 0, stream>>>(bufA, wtb1, bb1, bufB,
                                                          BATCH, 256, 512, 1);       // h1 -> B
    gemm_kernel<<<dim3(BATCH / 128, 1), 256, 0, stream>>>(bufB, wtb2, bb2, bufA,
                                                          BATCH, 128, 256, 1);       // bot -> A

    // interaction -> top_in (B, width 512)
    interact_kernel<<<BATCH / 4, 256, 0, stream>>>(cat, emb, bufA, bufB);

    // top MLP: t0/t1 on the 8-phase 256^2 pipeline, rest on 128^2
    gemm256_kernel<<<dim3(BATCH / 256, 4), 512, 0, stream>>>(bufB, wtt0, tb0, bufA,
                                                             BATCH, 1024, 512, 1);   // t0 -> A
    gemm256_kernel<<<dim3(BATCH / 256, 4), 512, 0, stream>>>(bufA, wtt1, tb1, bufB,
                                                             BATCH, 1024, 1024, 1);  // t1 -> B
    gemm_kernel<<<dim3(BATCH / 128, 4), 256, 0, stream>>>(bufB, wtt2, tb2, bufA,
                                                          BATCH, 512, 1024, 1);      // t2 -> A
    gemm_kernel<<<dim3(BATCH / 128, 2), 256, 0, stream>>>(bufA, wtt3, tb3, bufB,
                                                          BATCH, 256, 512, 1);       // t3 -> B
    out_kernel<<<BATCH / 4, 256, 0, stream>>>(bufB, tw4, tb4, out);
}